// Round 6
// baseline (251.373 us; speedup 1.0000x reference)
//
#include <hip/hip_runtime.h>
#include <hip/hip_bf16.h>
#include <math.h>

typedef __attribute__((ext_vector_type(8))) short s16x8;
typedef __attribute__((ext_vector_type(4))) float f32x4;
typedef __attribute__((ext_vector_type(2))) float v2f;

__device__ __forceinline__ unsigned short f2bf(float f) {
    union { float f; unsigned int u; } v; v.f = f;
    unsigned int u = v.u + 0x7FFFu + ((v.u >> 16) & 1u);
    return (unsigned short)(u >> 16);
}
__device__ __forceinline__ unsigned pk2(float lo, float hi) {
    __hip_bfloat162 h = __float22bfloat162_rn(make_float2(lo, hi));
    union { __hip_bfloat162 h; unsigned u; } v; v.h = h;
    return v.u;
}
// unpack uint (2 bf16) -> float2 {lo, hi}
__device__ __forceinline__ v2f up2(unsigned u) {
    union { unsigned u; float f; } a, b;
    a.u = u << 16; b.u = u & 0xffff0000u;
    v2f r; r.x = a.f; r.y = b.f; return r;
}

// ============ Fused prep kernel (block-specialized) ============
// b==0          : offset net -> shift table (soff/nsl) + effective weights (weff)
// b in [1,145)  : A2  (deform W, plain [o][tap*128+c] bf16)
// b in [145,289): Awf (tconv A, MFMA-fragment order)
// b in [289,801): xp  (x -> channels-last padded bf16)
__global__ __launch_bounds__(256) void k_prep(const float* __restrict__ x,
                                              const float* __restrict__ lat,
                                              const float* __restrict__ tw,
                                              const float* __restrict__ w1,
                                              const float* __restrict__ b1,
                                              const float* __restrict__ w2,
                                              const float* __restrict__ b2,
                                              unsigned short* __restrict__ xp,
                                              unsigned short* __restrict__ A2,
                                              unsigned short* __restrict__ Awf,
                                              int* __restrict__ soff_g,
                                              int* __restrict__ nsl_g,
                                              float* __restrict__ weff_g) {
    __shared__ float sm[8420];
    __shared__ int ish[200];
    int b = blockIdx.x, t = threadIdx.x;
    if (b == 0) {
        for (int i = t; i < 8192; i += 256) sm[(i >> 7) * 129 + (i & 127)] = w1[i * 9 + 4];
        __syncthreads();
        if (t < 128) {
            int n = t >> 6, o = t & 63;
            float s = b1[o];
            const float* ln = lat + n * 128;
#pragma unroll 8
            for (int c = 0; c < 128; ++c) s += ln[c] * sm[o * 129 + c];
            sm[8256 + t] = fmaxf(s, 0.f);
        }
        __syncthreads();
        if (t < 36) {
            int n = t / 18, j = t % 18;
            float s = b2[j];
            for (int o = 0; o < 64; ++o) s += sm[8256 + n * 64 + o] * w2[(j * 64 + o) * 9 + 4];
            float ov = tanhf(s);
            ov = fminf(fmaxf(ov, -0.999999f), 0.999999f);
            sm[8384 + t] = ov;
        }
        __syncthreads();
        if (t < 2) {
            int n2 = t;
            float* wl = &sm[n2 * 256];          // 25 slots x 9 taps
            int* dyA  = &ish[n2 * 100];
            int* dxA  = dyA + 25;
            int* keyA = dyA + 50;
            int* mapA = dyA + 75;
            for (int i = 0; i < 225; ++i) wl[i] = 0.f;
            for (int i = 0; i < 25; ++i) mapA[i] = -1;
            int ns = 0;
            for (int tap = 0; tap < 9; ++tap) {
                float oy = sm[8384 + n2 * 18 + 2 * tap];
                float ox = sm[8384 + n2 * 18 + 2 * tap + 1];
                float fly = floorf(oy), flx = floorf(ox);
                int iy = tap / 3 - 1 + (int)fly;
                int ix = tap % 3 - 1 + (int)flx;
                float fy = oy - fly, fx = ox - flx;
                for (int cr = 0; cr < 4; ++cr) {
                    int cy = cr >> 1, cx = cr & 1;
                    float wv = (cy ? fy : 1.f - fy) * (cx ? fx : 1.f - fx);
                    if (wv == 0.f) continue;
                    int dy = iy + cy, dx = ix + cx;
                    int sid = (dy + 2) * 5 + (dx + 2);
                    int s = mapA[sid];
                    if (s < 0) { s = ns; mapA[sid] = s; dyA[s] = dy; dxA[s] = dx; keyA[s] = sid; ++ns; }
                    wl[s * 9 + tap] += wv;
                }
            }
            // sort slots by (dy,dx) so B reads sweep rows monotonically (L1 reuse)
            for (int a = 0; a < ns - 1; ++a) {
                int m = a;
                for (int bq = a + 1; bq < ns; ++bq) if (keyA[bq] < keyA[m]) m = bq;
                if (m != a) {
                    int tmp;
                    tmp = keyA[a]; keyA[a] = keyA[m]; keyA[m] = tmp;
                    tmp = dyA[a];  dyA[a]  = dyA[m];  dyA[m]  = tmp;
                    tmp = dxA[a];  dxA[a]  = dxA[m];  dxA[m]  = tmp;
                    for (int e = 0; e < 9; ++e) {
                        float f = wl[a * 9 + e]; wl[a * 9 + e] = wl[m * 9 + e]; wl[m * 9 + e] = f;
                    }
                }
            }
            nsl_g[n2] = ns * 4;                 // K-chunks of 32
            for (int s = 0; s < ns; ++s)
                soff_g[n2 * 32 + s] = (dyA[s] * 132 + dxA[s]) * 128;
            for (int i = 0; i < 225; ++i) weff_g[n2 * 225 + i] = wl[i];
        }
    } else if (b < 145) {
        // A2 plain: A2[o*1152 + tap*128 + c] = bf16(tw[(o*128+c)*9+tap])
        int e0 = ((b - 1) * 256 + t) * 8;
        int o = e0 / 1152, rem = e0 - o * 1152;
        unsigned short v[8];
#pragma unroll
        for (int jj = 0; jj < 8; ++jj) {
            int kk = rem + jj;
            int tap = kk >> 7, c = kk & 127;
            v[jj] = f2bf(tw[(o * 128 + c) * 9 + tap]);
        }
        unsigned p0 = (unsigned)v[0] | ((unsigned)v[1] << 16);
        unsigned p1 = (unsigned)v[2] | ((unsigned)v[3] << 16);
        unsigned p2 = (unsigned)v[4] | ((unsigned)v[5] << 16);
        unsigned p3 = (unsigned)v[6] | ((unsigned)v[7] << 16);
        *(uint4*)(A2 + e0) = make_uint4(p0, p1, p2, p3);
    } else if (b < 289) {
        int slot = (b - 145) * 256 + t;
        int l = slot & 63;
        int mi = (slot >> 6) & 3;
        int wm = (slot >> 8) & 1;
        int k = slot >> 9;
        int row = wm * 64 + mi * 16 + (l & 15);
        int kq = l >> 4;
        unsigned short v[8];
#pragma unroll
        for (int jj = 0; jj < 8; ++jj) {
            int kcol = k * 32 + kq * 8 + jj;
            int t9 = kcol >> 8, ci = kcol & 255;
            int ky = t9 / 3, kx = t9 - ky * 3;
            v[jj] = f2bf(tw[(ci * 128 + row) * 9 + (2 - ky) * 3 + (2 - kx)]);
        }
        unsigned p0 = (unsigned)v[0] | ((unsigned)v[1] << 16);
        unsigned p1 = (unsigned)v[2] | ((unsigned)v[3] << 16);
        unsigned p2 = (unsigned)v[4] | ((unsigned)v[5] << 16);
        unsigned p3 = (unsigned)v[6] | ((unsigned)v[7] << 16);
        *(uint4*)(Awf + slot * 8) = make_uint4(p0, p1, p2, p3);
    } else {
        int bb = b - 289;
        int h = bb & 63, cq = (bb >> 6) & 3, n = bb >> 8;
        int c0 = cq * 64;
        {
            int wcol = t & 63, sub = t >> 6;
            for (int r = 0; r < 16; ++r) {
                int ci_l = r * 4 + sub;
                sm[ci_l * 65 + wcol] = x[((n * 256 + c0 + ci_l) * 64 + h) * 64 + wcol];
            }
        }
        __syncthreads();
        int wcol = t >> 2, cg = t & 3;
        unsigned short* dst = xp + (size_t)n * (65 * 65 * 256) + (h * 65 + wcol) * 256 + c0 + cg * 16;
        unsigned pk[8];
#pragma unroll
        for (int jj = 0; jj < 8; ++jj)
            pk[jj] = pk2(sm[(cg * 16 + 2 * jj) * 65 + wcol], sm[(cg * 16 + 2 * jj + 1) * 65 + wcol]);
        *(uint4*)dst = make_uint4(pk[0], pk[1], pk[2], pk[3]);
        *(uint4*)(dst + 8) = make_uint4(pk[4], pk[5], pk[6], pk[7]);
    }
}

// ============ build A' (shift-folded weights) in MFMA-fragment order ============
// A'[o][s*128+c] = sum_tap weff[s][tap] * W[o][tap][c]; grid = 2n x 100 chunk-blocks.
__global__ __launch_bounds__(256) void k_buildA(const unsigned short* __restrict__ A2,
                                                const float* __restrict__ weff_g,
                                                const int* __restrict__ nsl_g,
                                                unsigned short* __restrict__ Apf) {
    __shared__ float wt[9];
    int b = blockIdx.x;
    int n = b / 100, k = b % 100;
    if (k >= nsl_g[n]) return;                  // block-uniform
    int s = k >> 2, cq = k & 3;
    int t = threadIdx.x;
    if (t < 9) wt[t] = weff_g[n * 225 + s * 9 + t];
    __syncthreads();
    int w = t >> 6, mi = (t >> 4) & 3, lg = t & 15;
#pragma unroll
    for (int i = 0; i < 4; ++i) {
        int l = lg * 4 + i;
        int row = w * 64 + mi * 16 + (l & 15);
        int kq = l >> 4;
        int c0 = cq * 32 + kq * 8;
        const unsigned short* ap = A2 + row * 1152 + c0;
        v2f val[4] = {(v2f){0.f,0.f},(v2f){0.f,0.f},(v2f){0.f,0.f},(v2f){0.f,0.f}};
#pragma unroll
        for (int tap = 0; tap < 9; ++tap) {
            float wv = wt[tap];
            v2f wv2 = (v2f){wv, wv};
            uint4 u = *(const uint4*)(ap + tap * 128);
            val[0] += wv2 * up2(u.x);
            val[1] += wv2 * up2(u.y);
            val[2] += wv2 * up2(u.z);
            val[3] += wv2 * up2(u.w);
        }
        uint4 o4;
        o4.x = pk2(val[0].x, val[0].y);
        o4.y = pk2(val[1].x, val[1].y);
        o4.z = pk2(val[2].x, val[2].y);
        o4.w = pk2(val[3].x, val[3].y);
        *(uint4*)(Apf + (size_t)n * 819200 + ((((k * 4 + w) * 4 + mi) * 64 + l) * 8)) = o4;
    }
}

// ============ tconv: barrier-free, LDS-free MFMA GEMM (per-lane B fragments) ============
__global__ __launch_bounds__(256) void k_tconv4(const unsigned short* __restrict__ xp,
                                                const unsigned short* __restrict__ Awf,
                                                unsigned short* __restrict__ upp) {
    int t = threadIdx.x;
    int b = blockIdx.x;
    int cls = b >> 7;                       // heavy-first
    int phase = (cls < 2) ? 1 : 0;
    int xpar = 1 - (cls & 1);
    int idx = b & 127;
    int n = idx >> 6, yh = idx & 63;
    int y = 2 * yh + phase;
    const unsigned short* xpn = xp + (size_t)n * (65 * 65 * 256);

    int lane = t & 63, w = t >> 6;
    int col = lane & 15, q = lane >> 4;
    int pos = w * 16 + col;

    int nky = phase ? 2 : 1;
    int nkx = xpar ? 2 : 1;

    f32x4 acc[8];
#pragma unroll
    for (int mi = 0; mi < 8; ++mi) acc[mi] = (f32x4){0.f, 0.f, 0.f, 0.f};

    const unsigned short* Afl = Awf + lane * 8;

    for (int a1 = 0; a1 < nky; ++a1) {
        int ky = phase ? (a1 ? 2 : 0) : 1;
        int d2 = (y + ky - 1) >> 1;
        for (int a2 = 0; a2 < nkx; ++a2) {
            int kx = xpar ? (a2 ? 2 : 0) : 1;
            int s = (xpar + kx - 1) >> 1;
            int t9 = ky * 3 + kx;
            const unsigned short* bptr = xpn + ((size_t)(d2 * 65 + s + pos)) * 256 + q * 8;
            const unsigned short* aptr = Afl + t9 * 8 * 4096;
#pragma unroll 2
            for (int cb = 0; cb < 8; ++cb) {
                s16x8 bf = *(const s16x8*)(bptr + cb * 32);
                s16x8 a[8];
#pragma unroll
                for (int mi = 0; mi < 8; ++mi)
                    a[mi] = *(const s16x8*)(aptr + cb * 4096 + (mi >> 2) * 2048 + (mi & 3) * 512);
#pragma unroll
                for (int mi = 0; mi < 8; ++mi)
                    acc[mi] = __builtin_amdgcn_mfma_f32_16x16x32_bf16(a[mi], bf, acc[mi], 0, 0, 0);
            }
        }
    }

    unsigned short* uppn = upp + (size_t)n * (132 * 132 * 128);
    int xg = 2 * pos + xpar;
#pragma unroll
    for (int mi = 0; mi < 8; ++mi) {
        int co = mi * 16 + q * 4;
        unsigned short* p = uppn + ((y + 2) * 132 + (xg + 2)) * 128 + co;
        unsigned lo = pk2(acc[mi][0], acc[mi][1]);
        unsigned hi = pk2(acc[mi][2], acc[mi][3]);
        *(uint2*)p = make_uint2(lo, hi);
    }
}

// ============ deform: barrier-free LDS-free shift-GEMM ============
// out[n][o][y][x] = sum_{s,c} A'[o][s,c] * upp[n][y+2+dy(s)][x+2+dx(s)][c]
__global__ __launch_bounds__(256) void k_deform5(const unsigned short* __restrict__ upp,
                                                 const unsigned short* __restrict__ Apf,
                                                 const int* __restrict__ soff_g,
                                                 const int* __restrict__ nsl_g,
                                                 float* __restrict__ out) {
    int t = threadIdx.x;
    int b = blockIdx.x;
    int xcd = b & 7, j = b >> 3;
    int n = xcd >> 2, band = xcd & 3;
    int y = band * 32 + (j & 31);
    int tx0 = (j >> 5) * 64;
    const unsigned short* uppn = upp + (size_t)n * (132 * 132 * 128);

    int lane = t & 63, w = t >> 6;
    int col = lane & 15, q = lane >> 4;

    int nch = nsl_g[n];
    const int* soff = soff_g + n * 32;
    const unsigned short* Af = Apf + (size_t)n * 819200 + w * 2048 + lane * 8;
    int bb = ((y + 2) * 132 + (tx0 + 2)) * 128 + q * 8;

    f32x4 acc[4][4];
#pragma unroll
    for (int mi = 0; mi < 4; ++mi)
#pragma unroll
        for (int ni = 0; ni < 4; ++ni) acc[mi][ni] = (f32x4){0.f, 0.f, 0.f, 0.f};

    s16x8 a_c[4], b_c[4], a_n[4], b_n[4];
    {
        const unsigned short* bp = uppn + bb + soff[0];
#pragma unroll
        for (int ni = 0; ni < 4; ++ni)
            b_c[ni] = *(const s16x8*)(bp + (ni * 16 + col) * 128);
#pragma unroll
        for (int mi = 0; mi < 4; ++mi)
            a_c[mi] = *(const s16x8*)(Af + mi * 512);
    }

#pragma unroll 2
    for (int k = 0; k < nch; ++k) {
        int k1 = k + 1;
        if (k1 < nch) {
            const unsigned short* bp = uppn + bb + soff[k1 >> 2] + (k1 & 3) * 32;
#pragma unroll
            for (int ni = 0; ni < 4; ++ni)
                b_n[ni] = *(const s16x8*)(bp + (ni * 16 + col) * 128);
#pragma unroll
            for (int mi = 0; mi < 4; ++mi)
                a_n[mi] = *(const s16x8*)(Af + k1 * 8192 + mi * 512);
        }
#pragma unroll
        for (int mi = 0; mi < 4; ++mi)
#pragma unroll
            for (int ni = 0; ni < 4; ++ni)
                acc[mi][ni] = __builtin_amdgcn_mfma_f32_16x16x32_bf16(a_c[mi], b_c[ni], acc[mi][ni], 0, 0, 0);
        if (k1 < nch) {
#pragma unroll
            for (int i = 0; i < 4; ++i) { a_c[i] = a_n[i]; b_c[i] = b_n[i]; }
        }
    }

#pragma unroll
    for (int mi = 0; mi < 4; ++mi)
#pragma unroll
        for (int ni = 0; ni < 4; ++ni) {
            int o = w * 64 + mi * 16 + q * 4;
            int xg = tx0 + ni * 16 + col;
            float* p = out + (((size_t)(n * 256 + o)) * 128 + y) * 128 + xg;
            p[0]         = acc[mi][ni][0];
            p[16384]     = acc[mi][ni][1];
            p[2 * 16384] = acc[mi][ni][2];
            p[3 * 16384] = acc[mi][ni][3];
        }
}

extern "C" void kernel_launch(void* const* d_in, const int* in_sizes, int n_in,
                              void* d_out, int out_size, void* d_ws, size_t ws_size,
                              hipStream_t stream) {
    const float* x   = (const float*)d_in[0];
    const float* lat = (const float*)d_in[1];
    const float* tw  = (const float*)d_in[2];
    const float* w1  = (const float*)d_in[3];
    const float* b1  = (const float*)d_in[4];
    const float* w2  = (const float*)d_in[5];
    const float* b2  = (const float*)d_in[6];
    float* out = (float*)d_out;

    char* ws = (char*)d_ws;
    unsigned short* upp  = (unsigned short*)ws;                   // 8,921,088 B
    unsigned short* xp   = (unsigned short*)(ws + 8921088);       // 4,326,400 B
    unsigned short* Awf  = (unsigned short*)(ws + 13247488);      //   589,824 B
    unsigned short* A2   = (unsigned short*)(ws + 13837312);      //   589,824 B
    unsigned short* Apf  = (unsigned short*)(ws + 14427136);      // 3,276,800 B
    int*   soff          = (int*)(ws + 17703936);                 //       256 B
    int*   nsl           = (int*)(ws + 17704192);                 //         8 B
    float* weff          = (float*)(ws + 17704200);               //     1,800 B

    hipMemsetAsync(ws, 0, 13247488, stream);   // zero upp halo + xp pads
    k_prep<<<801, 256, 0, stream>>>(x, lat, tw, w1, b1, w2, b2, xp, A2, Awf, soff, nsl, weff);
    k_buildA<<<200, 256, 0, stream>>>(A2, weff, nsl, Apf);
    k_tconv4<<<512, 256, 0, stream>>>(xp, Awf, upp);
    k_deform5<<<512, 256, 0, stream>>>(upp, Apf, soff, nsl, out);
}

// Round 7
// 160.268 us; speedup vs baseline: 1.5685x; 1.5685x over previous
//
#include <hip/hip_runtime.h>
#include <hip/hip_bf16.h>
#include <math.h>

typedef __attribute__((ext_vector_type(8))) short s16x8;
typedef __attribute__((ext_vector_type(4))) float f32x4;
typedef __attribute__((ext_vector_type(2))) float v2f;

__device__ __forceinline__ unsigned short f2bf(float f) {
    union { float f; unsigned int u; } v; v.f = f;
    unsigned int u = v.u + 0x7FFFu + ((v.u >> 16) & 1u);
    return (unsigned short)(u >> 16);
}
__device__ __forceinline__ unsigned pk2(float lo, float hi) {
    __hip_bfloat162 h = __float22bfloat162_rn(make_float2(lo, hi));
    union { __hip_bfloat162 h; unsigned u; } v; v.h = h;
    return v.u;
}
__device__ __forceinline__ v2f up2(unsigned u) {
    union { unsigned u; float f; } a, b;
    a.u = u << 16; b.u = u & 0xffff0000u;
    v2f r; r.x = a.f; r.y = b.f; return r;
}

// blend 4 corner uint4s (8 bf16 ch each) with packed-f32 math, store packed bf16 uint4 to LDS
__device__ __forceinline__ void blend4(uint4 uA, uint4 uB, uint4 uC, uint4 uD,
                                       float4 cw, unsigned short* dst) {
    v2f c00 = (v2f){cw.x, cw.x}, c01 = (v2f){cw.y, cw.y};
    v2f c10 = (v2f){cw.z, cw.z}, c11 = (v2f){cw.w, cw.w};
    unsigned ua[4] = {uA.x, uA.y, uA.z, uA.w};
    unsigned ub[4] = {uB.x, uB.y, uB.z, uB.w};
    unsigned uc[4] = {uC.x, uC.y, uC.z, uC.w};
    unsigned ud[4] = {uD.x, uD.y, uD.z, uD.w};
    unsigned pk[4];
#pragma unroll
    for (int i = 0; i < 4; ++i) {
        v2f r = c00 * up2(ua[i]) + c01 * up2(ub[i]) + c10 * up2(uc[i]) + c11 * up2(ud[i]);
        pk[i] = pk2(r.x, r.y);
    }
    *(uint4*)dst = make_uint4(pk[0], pk[1], pk[2], pk[3]);
}

// ============ Fused prep kernel (block-specialized, verified R4) ============
// b==0: offset net -> ipar/fpar ; b in [1,145): A2f (deform A, frag-major)
// b in [145,289): Awf (tconv A, frag-major) ; b in [289,801): xp channels-last bf16
__global__ __launch_bounds__(256) void k_prep(const float* __restrict__ x,
                                              const float* __restrict__ lat,
                                              const float* __restrict__ tw,
                                              const float* __restrict__ w1,
                                              const float* __restrict__ b1,
                                              const float* __restrict__ w2,
                                              const float* __restrict__ b2,
                                              unsigned short* __restrict__ xp,
                                              unsigned short* __restrict__ A2f,
                                              unsigned short* __restrict__ Awf,
                                              int* __restrict__ ipar,
                                              float* __restrict__ fpar) {
    __shared__ float sm[8420];
    int b = blockIdx.x, t = threadIdx.x;
    if (b == 0) {
        for (int i = t; i < 8192; i += 256) sm[(i >> 7) * 129 + (i & 127)] = w1[i * 9 + 4];
        __syncthreads();
        if (t < 128) {
            int n = t >> 6, o = t & 63;
            float s = b1[o];
            const float* ln = lat + n * 128;
#pragma unroll 8
            for (int c = 0; c < 128; ++c) s += ln[c] * sm[o * 129 + c];
            sm[8256 + t] = fmaxf(s, 0.f);
        }
        __syncthreads();
        if (t < 36) {
            int n = t / 18, j = t % 18;
            float s = b2[j];
            for (int o = 0; o < 64; ++o) s += sm[8256 + n * 64 + o] * w2[(j * 64 + o) * 9 + 4];
            float ov = tanhf(s);
            ov = fminf(fmaxf(ov, -0.999999f), 0.999999f);
            sm[8384 + t] = ov;
        }
        __syncthreads();
        if (t < 36) {
            int n = t / 18, j = t % 18;
            int tap = j >> 1, d = j & 1;
            float ov = sm[8384 + t];
            float fl = floorf(ov);
            int kc = d ? (tap % 3) : (tap / 3);
            ipar[(n * 9 + tap) * 2 + d] = kc - 1 + (int)fl;
            fpar[(n * 9 + tap) * 2 + d] = ov - fl;
        }
    } else if (b < 145) {
        // A2f slot = ((k*4 + wm)*4 + mi)*64 + l ; elem = slot*8 + j
        int slot = (b - 1) * 256 + t;
        int l = slot & 63;
        int mi = (slot >> 6) & 3;
        int w = (slot >> 8) & 3;
        int k = slot >> 10;                 // 0..35
        int row = w * 64 + mi * 16 + (l & 15);
        int kq = l >> 4;
        unsigned short v[8];
#pragma unroll
        for (int j = 0; j < 8; ++j) {
            int kcol = k * 32 + kq * 8 + j;  // < 1152
            int tap = kcol >> 7, c = kcol & 127;
            v[j] = f2bf(tw[(row * 128 + c) * 9 + tap]);
        }
        unsigned p0 = (unsigned)v[0] | ((unsigned)v[1] << 16);
        unsigned p1 = (unsigned)v[2] | ((unsigned)v[3] << 16);
        unsigned p2 = (unsigned)v[4] | ((unsigned)v[5] << 16);
        unsigned p3 = (unsigned)v[6] | ((unsigned)v[7] << 16);
        *(uint4*)(A2f + slot * 8) = make_uint4(p0, p1, p2, p3);
    } else if (b < 289) {
        int slot = (b - 145) * 256 + t;
        int l = slot & 63;
        int mi = (slot >> 6) & 3;
        int wm = (slot >> 8) & 1;
        int k = slot >> 9;                  // 0..71
        int row = wm * 64 + mi * 16 + (l & 15);
        int kq = l >> 4;
        unsigned short v[8];
#pragma unroll
        for (int j = 0; j < 8; ++j) {
            int kcol = k * 32 + kq * 8 + j;  // < 2304
            int t9 = kcol >> 8, ci = kcol & 255;
            int ky = t9 / 3, kx = t9 - ky * 3;
            v[j] = f2bf(tw[(ci * 128 + row) * 9 + (2 - ky) * 3 + (2 - kx)]);
        }
        unsigned p0 = (unsigned)v[0] | ((unsigned)v[1] << 16);
        unsigned p1 = (unsigned)v[2] | ((unsigned)v[3] << 16);
        unsigned p2 = (unsigned)v[4] | ((unsigned)v[5] << 16);
        unsigned p3 = (unsigned)v[6] | ((unsigned)v[7] << 16);
        *(uint4*)(Awf + slot * 8) = make_uint4(p0, p1, p2, p3);
    } else {
        int bb = b - 289;
        int h = bb & 63, cq = (bb >> 6) & 3, n = bb >> 8;
        int c0 = cq * 64;
        {
            int wcol = t & 63, sub = t >> 6;
            for (int r = 0; r < 16; ++r) {
                int ci_l = r * 4 + sub;
                sm[ci_l * 65 + wcol] = x[((n * 256 + c0 + ci_l) * 64 + h) * 64 + wcol];
            }
        }
        __syncthreads();
        int wcol = t >> 2, cg = t & 3;
        unsigned short* dst = xp + (size_t)n * (65 * 65 * 256) + (h * 65 + wcol) * 256 + c0 + cg * 16;
        unsigned pk[8];
#pragma unroll
        for (int j = 0; j < 8; ++j)
            pk[j] = pk2(sm[(cg * 16 + 2 * j) * 65 + wcol], sm[(cg * 16 + 2 * j + 1) * 65 + wcol]);
        *(uint4*)dst = make_uint4(pk[0], pk[1], pk[2], pk[3]);
        *(uint4*)(dst + 8) = make_uint4(pk[4], pk[5], pk[6], pk[7]);
    }
}

// ============ tconv: barrier-free, LDS-free MFMA GEMM (verified R5) ============
__global__ __launch_bounds__(256) void k_tconv4(const unsigned short* __restrict__ xp,
                                                const unsigned short* __restrict__ Awf,
                                                unsigned short* __restrict__ upp) {
    int t = threadIdx.x;
    int b = blockIdx.x;
    int cls = b >> 7;
    int phase = (cls < 2) ? 1 : 0;
    int xpar = 1 - (cls & 1);
    int idx = b & 127;
    int n = idx >> 6, yh = idx & 63;
    int y = 2 * yh + phase;
    const unsigned short* xpn = xp + (size_t)n * (65 * 65 * 256);

    int lane = t & 63, w = t >> 6;
    int col = lane & 15, q = lane >> 4;
    int pos = w * 16 + col;

    int nky = phase ? 2 : 1;
    int nkx = xpar ? 2 : 1;

    f32x4 acc[8];
#pragma unroll
    for (int mi = 0; mi < 8; ++mi) acc[mi] = (f32x4){0.f, 0.f, 0.f, 0.f};

    const unsigned short* Afl = Awf + lane * 8;

    for (int a1 = 0; a1 < nky; ++a1) {
        int ky = phase ? (a1 ? 2 : 0) : 1;
        int d2 = (y + ky - 1) >> 1;
        for (int a2 = 0; a2 < nkx; ++a2) {
            int kx = xpar ? (a2 ? 2 : 0) : 1;
            int s = (xpar + kx - 1) >> 1;
            int t9 = ky * 3 + kx;
            const unsigned short* bptr = xpn + ((size_t)(d2 * 65 + s + pos)) * 256 + q * 8;
            const unsigned short* aptr = Afl + t9 * 8 * 4096;
#pragma unroll 2
            for (int cb = 0; cb < 8; ++cb) {
                s16x8 bf = *(const s16x8*)(bptr + cb * 32);
                s16x8 a[8];
#pragma unroll
                for (int mi = 0; mi < 8; ++mi)
                    a[mi] = *(const s16x8*)(aptr + cb * 4096 + (mi >> 2) * 2048 + (mi & 3) * 512);
#pragma unroll
                for (int mi = 0; mi < 8; ++mi)
                    acc[mi] = __builtin_amdgcn_mfma_f32_16x16x32_bf16(a[mi], bf, acc[mi], 0, 0, 0);
            }
        }
    }

    unsigned short* uppn = upp + (size_t)n * (132 * 132 * 128);
    int xg = 2 * pos + xpar;
#pragma unroll
    for (int mi = 0; mi < 8; ++mi) {
        int co = mi * 16 + q * 4;
        unsigned short* p = uppn + ((y + 2) * 132 + (xg + 2)) * 128 + co;
        unsigned lo = pk2(acc[mi][0], acc[mi][1]);
        unsigned hi = pk2(acc[mi][2], acc[mi][3]);
        *(uint2*)p = make_uint2(lo, hi);
    }
}

// ============ deform: 512-thread blocks (16 waves/CU), LDS-blend B, tap-space K=1152 ====
// 8 waves: wm = w&3 (M quarter), wn = w>>2 (N half). Wave tile 64x32, acc 4x2.
// 18 windows of K=64 (2 chunks), one barrier each; corners prefetched 1 window ahead,
// A fragments ping-pong prefetched per chunk.
__global__ __launch_bounds__(512, 4) void k_deform6(const unsigned short* __restrict__ upp,
                                                    const unsigned short* __restrict__ A2f,
                                                    const int* __restrict__ ipar,
                                                    const float* __restrict__ fpar,
                                                    float* __restrict__ out) {
    __shared__ unsigned short Bs[2][64][84];   // chunk c at short-col c*42
    __shared__ int sbase[9];
    __shared__ float4 swt[9];
    int t = threadIdx.x;
    int b = blockIdx.x;
    int xcd = b & 7, j = b >> 3;
    int n = xcd >> 2, band = xcd & 3;
    int y = band * 32 + (j & 31);
    int tx0 = (j >> 5) * 64;
    const unsigned short* uppn = upp + (size_t)n * (132 * 132 * 128);

    int lane = t & 63, w = t >> 6;      // w 0..7
    int wm = w & 3, wn = w >> 2;
    int col = lane & 15, q = lane >> 4;
    int bx = t >> 3, sub = t & 7;       // bx 0..63 position, sub selects (chunk, quad)
    int cst = sub >> 2, bcg = sub & 3;
    int boff = bx * 128 + cst * 32 + bcg * 8;

    if (t < 9) {
        int iy = ipar[(n * 9 + t) * 2 + 0], ix = ipar[(n * 9 + t) * 2 + 1];
        float fy = fpar[(n * 9 + t) * 2 + 0], fx = fpar[(n * 9 + t) * 2 + 1];
        sbase[t] = ((y + 2 + iy) * 132 + (tx0 + 2 + ix)) * 128;
        swt[t] = make_float4((1.f - fy) * (1.f - fx), (1.f - fy) * fx, fy * (1.f - fx), fy * fx);
    }

    f32x4 acc[4][2];
#pragma unroll
    for (int mi = 0; mi < 4; ++mi)
#pragma unroll
        for (int ni = 0; ni < 2; ++ni) acc[mi][ni] = (f32x4){0.f, 0.f, 0.f, 0.f};

    __syncthreads();   // sbase/swt visible

    const unsigned short* Afw = A2f + wm * 2048 + lane * 8;   // + chunk*8192 + mi*512
    s16x8 a_ev[4], a_od[4];
    uint4 cA, cB, cC, cD;     // corner prefetch (next window)
    float4 cwp;               // its blend weights

    // ---- prologue ----
    {
        // stage window 0 (tap 0, cb0 = 0)
        const unsigned short* p = uppn + sbase[0] + boff;
        uint4 uA = *(const uint4*)p;
        uint4 uB = *(const uint4*)(p + 128);
        uint4 uC = *(const uint4*)(p + 16896);
        uint4 uD = *(const uint4*)(p + 17024);
        blend4(uA, uB, uC, uD, swt[0], &Bs[0][bx][cst * 42 + bcg * 8]);
        // prefetch corners for window 1 (tap 0, cb0 = 64)
        const unsigned short* p2 = p + 64;
        cA = *(const uint4*)p2;
        cB = *(const uint4*)(p2 + 128);
        cC = *(const uint4*)(p2 + 16896);
        cD = *(const uint4*)(p2 + 17024);
        cwp = swt[0];
        // A fragments for chunk 0
#pragma unroll
        for (int mi = 0; mi < 4; ++mi)
            a_ev[mi] = *(const s16x8*)(Afw + mi * 512);
    }
    __syncthreads();

    for (int kk = 0; kk < 18; ++kk) {
        int cur = kk & 1;
        // blend+store window kk+1 from prefetched corners
        if (kk < 17)
            blend4(cA, cB, cC, cD, cwp, &Bs[cur ^ 1][bx][cst * 42 + bcg * 8]);
        // issue corner loads for window kk+2
        if (kk < 16) {
            int k2 = kk + 2;
            int tap2 = k2 >> 1, cb0 = (k2 & 1) * 64;
            cwp = swt[tap2];
            const unsigned short* p = uppn + sbase[tap2] + cb0 + boff;
            cA = *(const uint4*)p;
            cB = *(const uint4*)(p + 128);
            cC = *(const uint4*)(p + 16896);
            cD = *(const uint4*)(p + 17024);
        }
        // chunk 0 of window: issue odd-chunk A loads, MFMA even chunk
        {
            int nc = 2 * kk + 1;
#pragma unroll
            for (int mi = 0; mi < 4; ++mi)
                a_od[mi] = *(const s16x8*)(Afw + nc * 8192 + mi * 512);
            s16x8 bf[2];
#pragma unroll
            for (int ni = 0; ni < 2; ++ni)
                bf[ni] = *(const s16x8*)&Bs[cur][wn * 32 + ni * 16 + col][q * 8];
#pragma unroll
            for (int mi = 0; mi < 4; ++mi)
#pragma unroll
                for (int ni = 0; ni < 2; ++ni)
                    acc[mi][ni] = __builtin_amdgcn_mfma_f32_16x16x32_bf16(a_ev[mi], bf[ni], acc[mi][ni], 0, 0, 0);
        }
        // chunk 1: issue next window's even-chunk A loads, MFMA odd chunk
        {
            if (kk < 17) {
                int nc = 2 * (kk + 1);
#pragma unroll
                for (int mi = 0; mi < 4; ++mi)
                    a_ev[mi] = *(const s16x8*)(Afw + nc * 8192 + mi * 512);
            }
            s16x8 bf[2];
#pragma unroll
            for (int ni = 0; ni < 2; ++ni)
                bf[ni] = *(const s16x8*)&Bs[cur][wn * 32 + ni * 16 + col][42 + q * 8];
#pragma unroll
            for (int mi = 0; mi < 4; ++mi)
#pragma unroll
                for (int ni = 0; ni < 2; ++ni)
                    acc[mi][ni] = __builtin_amdgcn_mfma_f32_16x16x32_bf16(a_od[mi], bf[ni], acc[mi][ni], 0, 0, 0);
        }
        __syncthreads();
    }

#pragma unroll
    for (int mi = 0; mi < 4; ++mi)
#pragma unroll
        for (int ni = 0; ni < 2; ++ni) {
            int o = wm * 64 + mi * 16 + q * 4;
            int xg = tx0 + wn * 32 + ni * 16 + col;
            float* p = out + (((size_t)(n * 256 + o)) * 128 + y) * 128 + xg;
            p[0]         = acc[mi][ni][0];
            p[16384]     = acc[mi][ni][1];
            p[2 * 16384] = acc[mi][ni][2];
            p[3 * 16384] = acc[mi][ni][3];
        }
}

extern "C" void kernel_launch(void* const* d_in, const int* in_sizes, int n_in,
                              void* d_out, int out_size, void* d_ws, size_t ws_size,
                              hipStream_t stream) {
    const float* x   = (const float*)d_in[0];
    const float* lat = (const float*)d_in[1];
    const float* tw  = (const float*)d_in[2];
    const float* w1  = (const float*)d_in[3];
    const float* b1  = (const float*)d_in[4];
    const float* w2  = (const float*)d_in[5];
    const float* b2  = (const float*)d_in[6];
    float* out = (float*)d_out;

    char* ws = (char*)d_ws;
    unsigned short* upp = (unsigned short*)ws;                   // 8,921,088 B
    unsigned short* xp  = (unsigned short*)(ws + 8921088);       // 4,326,400 B
    unsigned short* A2f = (unsigned short*)(ws + 13247488);      //   589,824 B
    unsigned short* Awf = (unsigned short*)(ws + 13837312);      //   589,824 B
    int*   ipar         = (int*)(ws + 14427136);
    float* fpar         = (float*)(ws + 14427424);

    hipMemsetAsync(ws, 0, 13247488, stream);   // zero upp halo + xp pads
    k_prep<<<801, 256, 0, stream>>>(x, lat, tw, w1, b1, w2, b2, xp, A2f, Awf, ipar, fpar);
    k_tconv4<<<512, 256, 0, stream>>>(xp, Awf, upp);
    k_deform6<<<512, 512, 0, stream>>>(upp, A2f, ipar, fpar, out);
}

// Round 8
// 157.336 us; speedup vs baseline: 1.5977x; 1.0186x over previous
//
#include <hip/hip_runtime.h>
#include <hip/hip_bf16.h>
#include <math.h>

typedef __attribute__((ext_vector_type(8))) short s16x8;
typedef __attribute__((ext_vector_type(4))) float f32x4;
typedef __attribute__((ext_vector_type(2))) float v2f;

__device__ __forceinline__ unsigned short f2bf(float f) {
    union { float f; unsigned int u; } v; v.f = f;
    unsigned int u = v.u + 0x7FFFu + ((v.u >> 16) & 1u);
    return (unsigned short)(u >> 16);
}
__device__ __forceinline__ unsigned pk2(float lo, float hi) {
    __hip_bfloat162 h = __float22bfloat162_rn(make_float2(lo, hi));
    union { __hip_bfloat162 h; unsigned u; } v; v.h = h;
    return v.u;
}
__device__ __forceinline__ v2f up2(unsigned u) {
    union { unsigned u; float f; } a, b;
    a.u = u << 16; b.u = u & 0xffff0000u;
    v2f r; r.x = a.f; r.y = b.f; return r;
}

// blend 4 corner uint4s (8 bf16 ch each) with packed-f32 math, store packed bf16 uint4 to LDS
__device__ __forceinline__ void blend4(uint4 uA, uint4 uB, uint4 uC, uint4 uD,
                                       float4 cw, unsigned short* dst) {
    v2f c00 = (v2f){cw.x, cw.x}, c01 = (v2f){cw.y, cw.y};
    v2f c10 = (v2f){cw.z, cw.z}, c11 = (v2f){cw.w, cw.w};
    unsigned ua[4] = {uA.x, uA.y, uA.z, uA.w};
    unsigned ub[4] = {uB.x, uB.y, uB.z, uB.w};
    unsigned uc[4] = {uC.x, uC.y, uC.z, uC.w};
    unsigned ud[4] = {uD.x, uD.y, uD.z, uD.w};
    unsigned pk[4];
#pragma unroll
    for (int i = 0; i < 4; ++i) {
        v2f r = c00 * up2(ua[i]) + c01 * up2(ub[i]) + c10 * up2(uc[i]) + c11 * up2(ud[i]);
        pk[i] = pk2(r.x, r.y);
    }
    *(uint4*)dst = make_uint4(pk[0], pk[1], pk[2], pk[3]);
}

// ============ Fused prep kernel (block-specialized) ============
// b==0: offset net ; b in [1,145): A2f ; b in [145,289): Awf ;
// b in [289,801): xp interior ; b in [801,803): xp pad zeroing (row/col 64)
__global__ __launch_bounds__(256) void k_prep(const float* __restrict__ x,
                                              const float* __restrict__ lat,
                                              const float* __restrict__ tw,
                                              const float* __restrict__ w1,
                                              const float* __restrict__ b1,
                                              const float* __restrict__ w2,
                                              const float* __restrict__ b2,
                                              unsigned short* __restrict__ xp,
                                              unsigned short* __restrict__ A2f,
                                              unsigned short* __restrict__ Awf,
                                              int* __restrict__ ipar,
                                              float* __restrict__ fpar) {
    __shared__ float sm[8420];
    int b = blockIdx.x, t = threadIdx.x;
    if (b == 0) {
        for (int i = t; i < 8192; i += 256) sm[(i >> 7) * 129 + (i & 127)] = w1[i * 9 + 4];
        __syncthreads();
        if (t < 128) {
            int n = t >> 6, o = t & 63;
            float s = b1[o];
            const float* ln = lat + n * 128;
#pragma unroll 8
            for (int c = 0; c < 128; ++c) s += ln[c] * sm[o * 129 + c];
            sm[8256 + t] = fmaxf(s, 0.f);
        }
        __syncthreads();
        if (t < 36) {
            int n = t / 18, j = t % 18;
            float s = b2[j];
            for (int o = 0; o < 64; ++o) s += sm[8256 + n * 64 + o] * w2[(j * 64 + o) * 9 + 4];
            float ov = tanhf(s);
            ov = fminf(fmaxf(ov, -0.999999f), 0.999999f);
            sm[8384 + t] = ov;
        }
        __syncthreads();
        if (t < 36) {
            int n = t / 18, j = t % 18;
            int tap = j >> 1, d = j & 1;
            float ov = sm[8384 + t];
            float fl = floorf(ov);
            int kc = d ? (tap % 3) : (tap / 3);
            ipar[(n * 9 + tap) * 2 + d] = kc - 1 + (int)fl;
            fpar[(n * 9 + tap) * 2 + d] = ov - fl;
        }
    } else if (b < 145) {
        int slot = (b - 1) * 256 + t;
        int l = slot & 63;
        int mi = (slot >> 6) & 3;
        int w = (slot >> 8) & 3;
        int k = slot >> 10;
        int row = w * 64 + mi * 16 + (l & 15);
        int kq = l >> 4;
        unsigned short v[8];
#pragma unroll
        for (int j = 0; j < 8; ++j) {
            int kcol = k * 32 + kq * 8 + j;
            int tap = kcol >> 7, c = kcol & 127;
            v[j] = f2bf(tw[(row * 128 + c) * 9 + tap]);
        }
        unsigned p0 = (unsigned)v[0] | ((unsigned)v[1] << 16);
        unsigned p1 = (unsigned)v[2] | ((unsigned)v[3] << 16);
        unsigned p2 = (unsigned)v[4] | ((unsigned)v[5] << 16);
        unsigned p3 = (unsigned)v[6] | ((unsigned)v[7] << 16);
        *(uint4*)(A2f + slot * 8) = make_uint4(p0, p1, p2, p3);
    } else if (b < 289) {
        int slot = (b - 145) * 256 + t;
        int l = slot & 63;
        int mi = (slot >> 6) & 3;
        int wm = (slot >> 8) & 1;
        int k = slot >> 9;
        int row = wm * 64 + mi * 16 + (l & 15);
        int kq = l >> 4;
        unsigned short v[8];
#pragma unroll
        for (int j = 0; j < 8; ++j) {
            int kcol = k * 32 + kq * 8 + j;
            int t9 = kcol >> 8, ci = kcol & 255;
            int ky = t9 / 3, kx = t9 - ky * 3;
            v[j] = f2bf(tw[(ci * 128 + row) * 9 + (2 - ky) * 3 + (2 - kx)]);
        }
        unsigned p0 = (unsigned)v[0] | ((unsigned)v[1] << 16);
        unsigned p1 = (unsigned)v[2] | ((unsigned)v[3] << 16);
        unsigned p2 = (unsigned)v[4] | ((unsigned)v[5] << 16);
        unsigned p3 = (unsigned)v[6] | ((unsigned)v[7] << 16);
        *(uint4*)(Awf + slot * 8) = make_uint4(p0, p1, p2, p3);
    } else if (b < 801) {
        int bb = b - 289;
        int h = bb & 63, cq = (bb >> 6) & 3, n = bb >> 8;
        int c0 = cq * 64;
        {
            int wcol = t & 63, sub = t >> 6;
            for (int r = 0; r < 16; ++r) {
                int ci_l = r * 4 + sub;
                sm[ci_l * 65 + wcol] = x[((n * 256 + c0 + ci_l) * 64 + h) * 64 + wcol];
            }
        }
        __syncthreads();
        int wcol = t >> 2, cg = t & 3;
        unsigned short* dst = xp + (size_t)n * (65 * 65 * 256) + (h * 65 + wcol) * 256 + c0 + cg * 16;
        unsigned pk[8];
#pragma unroll
        for (int j = 0; j < 8; ++j)
            pk[j] = pk2(sm[(cg * 16 + 2 * j) * 65 + wcol], sm[(cg * 16 + 2 * j + 1) * 65 + wcol]);
        *(uint4*)dst = make_uint4(pk[0], pk[1], pk[2], pk[3]);
        *(uint4*)(dst + 8) = make_uint4(pk[4], pk[5], pk[6], pk[7]);
    } else {
        // zero xp pads: row h=64 (65 cols) + col w=64 (h 0..63): 129 positions x 256 ch
        int n = b - 801;
        unsigned short* xpn = xp + (size_t)n * (65 * 65 * 256);
        uint4 z = make_uint4(0u, 0u, 0u, 0u);
        for (int i = t; i < 129 * 16; i += 256) {
            int pos = i >> 4, seg = i & 15;
            int h, wv;
            if (pos < 65) { h = 64; wv = pos; } else { h = pos - 65; wv = 64; }
            *(uint4*)(xpn + (h * 65 + wv) * 256 + seg * 16) = z;
        }
    }
}

// ============ tconv: barrier-free, LDS-free MFMA GEMM (verified R5) + halo zeroing ============
__global__ __launch_bounds__(256) void k_tconv4(const unsigned short* __restrict__ xp,
                                                const unsigned short* __restrict__ Awf,
                                                unsigned short* __restrict__ upp) {
    int t = threadIdx.x;
    int b = blockIdx.x;
    if (b >= 512) {
        // zero upp halo: 1040 positions (4 full rows + 4 cols x 128 rows) x 128 ch, per n split in 2
        int hb = b - 512;
        int n = hb >> 1, half = hb & 1;
        unsigned short* uppn = upp + (size_t)n * (132 * 132 * 128);
        uint4 z = make_uint4(0u, 0u, 0u, 0u);
        const int rows4[4] = {0, 1, 130, 131};
        for (int i = t; i < 8320; i += 256) {         // 520 pos * 16 segs
            int u = half * 8320 + i;
            int pos = u >> 4, seg = u & 15;
            int y, xx;
            if (pos < 528) { y = rows4[pos / 132]; xx = pos % 132; }
            else { int j = pos - 528; y = 2 + (j >> 2); xx = rows4[j & 3] ; }
            // cols subset for side strips: {0,1,130,131}
            *(uint4*)(uppn + (y * 132 + xx) * 128 + seg * 8) = z;
        }
        return;
    }
    int cls = b >> 7;
    int phase = (cls < 2) ? 1 : 0;
    int xpar = 1 - (cls & 1);
    int idx = b & 127;
    int n = idx >> 6, yh = idx & 63;
    int y = 2 * yh + phase;
    const unsigned short* xpn = xp + (size_t)n * (65 * 65 * 256);

    int lane = t & 63, w = t >> 6;
    int col = lane & 15, q = lane >> 4;
    int pos = w * 16 + col;

    int nky = phase ? 2 : 1;
    int nkx = xpar ? 2 : 1;

    f32x4 acc[8];
#pragma unroll
    for (int mi = 0; mi < 8; ++mi) acc[mi] = (f32x4){0.f, 0.f, 0.f, 0.f};

    const unsigned short* Afl = Awf + lane * 8;

    for (int a1 = 0; a1 < nky; ++a1) {
        int ky = phase ? (a1 ? 2 : 0) : 1;
        int d2 = (y + ky - 1) >> 1;
        for (int a2 = 0; a2 < nkx; ++a2) {
            int kx = xpar ? (a2 ? 2 : 0) : 1;
            int s = (xpar + kx - 1) >> 1;
            int t9 = ky * 3 + kx;
            const unsigned short* bptr = xpn + ((size_t)(d2 * 65 + s + pos)) * 256 + q * 8;
            const unsigned short* aptr = Afl + t9 * 8 * 4096;
#pragma unroll 2
            for (int cb = 0; cb < 8; ++cb) {
                s16x8 bf = *(const s16x8*)(bptr + cb * 32);
                s16x8 a[8];
#pragma unroll
                for (int mi = 0; mi < 8; ++mi)
                    a[mi] = *(const s16x8*)(aptr + cb * 4096 + (mi >> 2) * 2048 + (mi & 3) * 512);
#pragma unroll
                for (int mi = 0; mi < 8; ++mi)
                    acc[mi] = __builtin_amdgcn_mfma_f32_16x16x32_bf16(a[mi], bf, acc[mi], 0, 0, 0);
            }
        }
    }

    unsigned short* uppn = upp + (size_t)n * (132 * 132 * 128);
    int xg = 2 * pos + xpar;
#pragma unroll
    for (int mi = 0; mi < 8; ++mi) {
        int co = mi * 16 + q * 4;
        unsigned short* p = uppn + ((y + 2) * 132 + (xg + 2)) * 128 + co;
        unsigned lo = pk2(acc[mi][0], acc[mi][1]);
        unsigned hi = pk2(acc[mi][2], acc[mi][3]);
        *(uint2*)p = make_uint2(lo, hi);
    }
}

// ============ deform: 512-thr, LDS-blend B, blend-at-END windows (barrier drains nothing) ====
// Window kk: [issue corners kk+1] -> MFMA chunk0 -> MFMA chunk1 -> blend->Bs[next] -> barrier.
// Corner loads are consumed in-window (after ~2 MFMA blocks of latency cover), so the
// compiler's vmcnt(0) at __syncthreads has (almost) nothing left to drain.
__global__ __launch_bounds__(512, 4) void k_deform7(const unsigned short* __restrict__ upp,
                                                    const unsigned short* __restrict__ A2f,
                                                    const int* __restrict__ ipar,
                                                    const float* __restrict__ fpar,
                                                    float* __restrict__ out) {
    __shared__ unsigned short Bs[2][64][84];   // chunk c at short-col c*42
    __shared__ int sbase[9];
    __shared__ float4 swt[9];
    int t = threadIdx.x;
    int b = blockIdx.x;
    int xcd = b & 7, j = b >> 3;
    int n = xcd >> 2, band = xcd & 3;
    int y = band * 32 + (j & 31);
    int tx0 = (j >> 5) * 64;
    const unsigned short* uppn = upp + (size_t)n * (132 * 132 * 128);

    int lane = t & 63, w = t >> 6;      // w 0..7
    int wm = w & 3, wn = w >> 2;
    int col = lane & 15, q = lane >> 4;
    int bx = t >> 3, sub = t & 7;
    int cst = sub >> 2, bcg = sub & 3;
    int boff = bx * 128 + cst * 32 + bcg * 8;

    if (t < 9) {
        int iy = ipar[(n * 9 + t) * 2 + 0], ix = ipar[(n * 9 + t) * 2 + 1];
        float fy = fpar[(n * 9 + t) * 2 + 0], fx = fpar[(n * 9 + t) * 2 + 1];
        sbase[t] = ((y + 2 + iy) * 132 + (tx0 + 2 + ix)) * 128;
        swt[t] = make_float4((1.f - fy) * (1.f - fx), (1.f - fy) * fx, fy * (1.f - fx), fy * fx);
    }

    f32x4 acc[4][2];
#pragma unroll
    for (int mi = 0; mi < 4; ++mi)
#pragma unroll
        for (int ni = 0; ni < 2; ++ni) acc[mi][ni] = (f32x4){0.f, 0.f, 0.f, 0.f};

    __syncthreads();   // sbase/swt visible

    const unsigned short* Afw = A2f + wm * 2048 + lane * 8;   // + chunk*8192 + mi*512
    s16x8 a_cur[4], a_nxt[4];
    uint4 cA, cB, cC, cD;
    float4 cwp;

    // ---- prologue: stage window 0, load A chunk 0 ----
    {
        const unsigned short* p = uppn + sbase[0] + boff;
        uint4 uA = *(const uint4*)p;
        uint4 uB = *(const uint4*)(p + 128);
        uint4 uC = *(const uint4*)(p + 16896);
        uint4 uD = *(const uint4*)(p + 17024);
#pragma unroll
        for (int mi = 0; mi < 4; ++mi)
            a_cur[mi] = *(const s16x8*)(Afw + mi * 512);
        blend4(uA, uB, uC, uD, swt[0], &Bs[0][bx][cst * 42 + bcg * 8]);
    }
    __syncthreads();

    for (int kk = 0; kk < 18; ++kk) {
        int cur = kk & 1;
        // top of window: issue corner loads for window kk+1
        if (kk < 17) {
            int k1 = kk + 1;
            int tap1 = k1 >> 1, cb0 = (k1 & 1) * 64;
            cwp = swt[tap1];
            const unsigned short* p = uppn + sbase[tap1] + cb0 + boff;
            cA = *(const uint4*)p;
            cB = *(const uint4*)(p + 128);
            cC = *(const uint4*)(p + 16896);
            cD = *(const uint4*)(p + 17024);
        }
        // chunk 0: prefetch A for chunk 1, MFMA chunk 0
        {
#pragma unroll
            for (int mi = 0; mi < 4; ++mi)
                a_nxt[mi] = *(const s16x8*)(Afw + (2 * kk + 1) * 8192 + mi * 512);
            s16x8 bf[2];
#pragma unroll
            for (int ni = 0; ni < 2; ++ni)
                bf[ni] = *(const s16x8*)&Bs[cur][wn * 32 + ni * 16 + col][q * 8];
#pragma unroll
            for (int mi = 0; mi < 4; ++mi)
#pragma unroll
                for (int ni = 0; ni < 2; ++ni)
                    acc[mi][ni] = __builtin_amdgcn_mfma_f32_16x16x32_bf16(a_cur[mi], bf[ni], acc[mi][ni], 0, 0, 0);
#pragma unroll
            for (int mi = 0; mi < 4; ++mi) a_cur[mi] = a_nxt[mi];
        }
        // chunk 1: prefetch A for next window's chunk 0, MFMA chunk 1
        {
            if (kk < 17) {
#pragma unroll
                for (int mi = 0; mi < 4; ++mi)
                    a_nxt[mi] = *(const s16x8*)(Afw + (2 * kk + 2) * 8192 + mi * 512);
            }
            s16x8 bf[2];
#pragma unroll
            for (int ni = 0; ni < 2; ++ni)
                bf[ni] = *(const s16x8*)&Bs[cur][wn * 32 + ni * 16 + col][42 + q * 8];
#pragma unroll
            for (int mi = 0; mi < 4; ++mi)
#pragma unroll
                for (int ni = 0; ni < 2; ++ni)
                    acc[mi][ni] = __builtin_amdgcn_mfma_f32_16x16x32_bf16(a_cur[mi], bf[ni], acc[mi][ni], 0, 0, 0);
#pragma unroll
            for (int mi = 0; mi < 4; ++mi) a_cur[mi] = a_nxt[mi];
        }
        // end of window: blend the corners issued at the top -> Bs[next]
        if (kk < 17)
            blend4(cA, cB, cC, cD, cwp, &Bs[cur ^ 1][bx][cst * 42 + bcg * 8]);
        __syncthreads();
    }

#pragma unroll
    for (int mi = 0; mi < 4; ++mi)
#pragma unroll
        for (int ni = 0; ni < 2; ++ni) {
            int o = wm * 64 + mi * 16 + q * 4;
            int xg = tx0 + wn * 32 + ni * 16 + col;
            float* p = out + (((size_t)(n * 256 + o)) * 128 + y) * 128 + xg;
            p[0]         = acc[mi][ni][0];
            p[16384]     = acc[mi][ni][1];
            p[2 * 16384] = acc[mi][ni][2];
            p[3 * 16384] = acc[mi][ni][3];
        }
}

extern "C" void kernel_launch(void* const* d_in, const int* in_sizes, int n_in,
                              void* d_out, int out_size, void* d_ws, size_t ws_size,
                              hipStream_t stream) {
    const float* x   = (const float*)d_in[0];
    const float* lat = (const float*)d_in[1];
    const float* tw  = (const float*)d_in[2];
    const float* w1  = (const float*)d_in[3];
    const float* b1  = (const float*)d_in[4];
    const float* w2  = (const float*)d_in[5];
    const float* b2  = (const float*)d_in[6];
    float* out = (float*)d_out;

    char* ws = (char*)d_ws;
    unsigned short* upp = (unsigned short*)ws;                   // 8,921,088 B
    unsigned short* xp  = (unsigned short*)(ws + 8921088);       // 4,326,400 B
    unsigned short* A2f = (unsigned short*)(ws + 13247488);      //   589,824 B
    unsigned short* Awf = (unsigned short*)(ws + 13837312);      //   589,824 B
    int*   ipar         = (int*)(ws + 14427136);
    float* fpar         = (float*)(ws + 14427424);

    k_prep<<<803, 256, 0, stream>>>(x, lat, tw, w1, b1, w2, b2, xp, A2f, Awf, ipar, fpar);
    k_tconv4<<<516, 256, 0, stream>>>(xp, Awf, upp);
    k_deform7<<<512, 512, 0, stream>>>(upp, A2f, ipar, fpar, out);
}